// Round 10
// baseline (540.819 us; speedup 1.0000x reference)
//
#include <hip/hip_runtime.h>
#include <hip/hip_bf16.h>
#include <hip/hip_fp16.h>

#define NN 100000
#define NE 1600000
#define FIN 128
#define HD 64
#define NB_SCAN 391    // ceil(NN/256)
#define NB_MM 782      // ceil(NN/128): 128 nodes per k_mm block
#define BSH 9          // bucket covers 512 dest nodes
#define NBUCK 196      // ceil(NN/512)
#define BCAP 10240     // per-bucket staging cap (mean 8163, sigma 128 -> +16 sigma)
#define CHUNK 4096     // edges per stage-1 block
#define NCHUNK 391     // ceil(NE/CHUNK)
#define EBLOCKS 2048   // edge-kernel blocks (8192 waves)

typedef unsigned int uint32;

// ---------------- stage 1: block-level counting sort into 196 buckets ----------------
__global__ void __launch_bounds__(256) k_part(const int* __restrict__ row,
                                              const int* __restrict__ col,
                                              int* __restrict__ bcnt,
                                              uint32* __restrict__ staged){
    __shared__ int hist[NBUCK];
    __shared__ int base[NBUCK];
    int t = threadIdx.x;
    int e0 = blockIdx.x * CHUNK;
    int e1 = min(e0 + CHUNK, NE);
    for(int i = t; i < NBUCK; i += 256) hist[i] = 0;
    __syncthreads();
    for(int e = e0 + t; e < e1; e += 256)
        atomicAdd(&hist[col[e] >> BSH], 1);
    __syncthreads();
    for(int i = t; i < NBUCK; i += 256){
        int c = hist[i];
        base[i] = (c > 0) ? atomicAdd(&bcnt[i], c) : 0;   // one global atomic per (block,bucket)
        hist[i] = 0;                                       // reuse as cursor
    }
    __syncthreads();
    for(int e = e0 + t; e < e1; e += 256){
        int c = col[e], r = row[e];
        int b = c >> BSH;
        int pos = base[b] + atomicAdd(&hist[b], 1);
        if(pos < BCAP)
            staged[(size_t)b*BCAP + pos] = ((uint32)r << BSH) | (uint32)(c & 511);
    }
}

// ---------------- stage 2a: per-bucket LDS histogram -> deg ----------------
__global__ void __launch_bounds__(256) k_hist(const int* __restrict__ bcnt,
                                              const uint32* __restrict__ staged,
                                              int* __restrict__ deg){
    __shared__ int h[512];
    int b = blockIdx.x, t = threadIdx.x;
    for(int i = t; i < 512; i += 256) h[i] = 0;
    __syncthreads();
    int cnt = min(bcnt[b], BCAP);
    const uint32* st = staged + (size_t)b*BCAP;
    for(int i = t; i < cnt; i += 256) atomicAdd(&h[st[i] & 511u], 1);
    __syncthreads();
    for(int i = t; i < 512; i += 256){
        int n = b*512 + i;
        if(n < NN) deg[n] = h[i];
    }
}

// ---------------- scan chain (deg -> starts, dinv) ----------------
__global__ void k_bsum(const int* __restrict__ deg, int* __restrict__ bsum){
    __shared__ int r[256];
    int t = threadIdx.x; int i = blockIdx.x*256 + t;
    r[t] = (i < NN) ? deg[i] : 0;
    __syncthreads();
    for(int off=128; off>0; off>>=1){ if(t<off) r[t]+=r[t+off]; __syncthreads(); }
    if(t==0) bsum[blockIdx.x] = r[0];
}

__global__ void k_top(int* __restrict__ bsum){
    __shared__ int s[512];
    int t = threadIdx.x;
    int v = (t < NB_SCAN) ? bsum[t] : 0;
    s[t] = v; __syncthreads();
    for(int off=1; off<512; off<<=1){
        int a = (t>=off)? s[t-off] : 0;
        __syncthreads();
        s[t] += a;
        __syncthreads();
    }
    if(t < NB_SCAN) bsum[t] = s[t] - v;   // exclusive scan of block sums
}

__global__ void k_scan(const int* __restrict__ deg, const int* __restrict__ bsum,
                       int* __restrict__ starts, float* __restrict__ dinv){
    __shared__ int s[256];
    int t = threadIdx.x; int i = blockIdx.x*256 + t;
    int d = (i<NN)? deg[i] : 0;
    s[t] = d; __syncthreads();
    for(int off=1; off<256; off<<=1){
        int a = (t>=off)? s[t-off] : 0;
        __syncthreads();
        s[t] += a;
        __syncthreads();
    }
    if(i < NN){
        starts[i] = bsum[blockIdx.x] + s[t] - d;   // exclusive
        dinv[i] = rsqrtf((float)(d + 1));          // +1 self-loop
    }
}

// ---------------- stage 2b: per-bucket LDS scatter, coalesced csr write ----------------
__global__ void __launch_bounds__(256) k_fill2(const int* __restrict__ bcnt,
                                               const uint32* __restrict__ staged,
                                               const int* __restrict__ starts,
                                               int* __restrict__ csr){
    __shared__ int cur[512];
    __shared__ int lcsr[BCAP];
    int b = blockIdx.x, t = threadIdx.x;
    int n0 = b*512;
    int base = starts[n0];
    for(int i = t; i < 512; i += 256){
        int n = n0 + i;
        cur[i] = (n < NN) ? starts[n] - base : 0;
    }
    __syncthreads();
    int cnt = min(bcnt[b], BCAP);
    const uint32* st = staged + (size_t)b*BCAP;
    for(int i = t; i < cnt; i += 256){
        uint32 u = st[i];
        int p = atomicAdd(&cur[u & 511u], 1);
        lcsr[p] = (int)(u >> BSH);
    }
    __syncthreads();
    for(int i = t; i < cnt; i += 256) csr[base + i] = lcsr[i];
}

// ---------------- BN constant folding ----------------
__global__ void k_const(const float* __restrict__ encB, const float* __restrict__ encG,
                        const float* __restrict__ encBe, const float* __restrict__ encM,
                        const float* __restrict__ encV,
                        const float* __restrict__ ep1b, const float* __restrict__ epG,
                        const float* __restrict__ epBe, const float* __restrict__ epM,
                        const float* __restrict__ epV,
                        float* __restrict__ foldEnc, float* __restrict__ foldPre){
    int j = threadIdx.x;
    if(j < 64){
        float s = encG[j]*rsqrtf(encV[j]+1e-5f);
        foldEnc[j]      = s;
        foldEnc[64+j]   = (encB[j]-encM[j])*s + encBe[j];
        float sp = epG[j]*rsqrtf(epV[j]+1e-5f);
        foldPre[j]      = sp;
        foldPre[64+j]   = sp;
        foldPre[128+j]  = sp*(ep1b[j]-epM[j]) + epBe[j];
        foldPre[192+j]  = 0.f;
    }
}

// ---------------- register-blocked GEMM: 128 nodes x 64 j per block ----------------
// 256 threads = 32 node-quads x 8 j-groups; thread = 4 nodes x 8 j micro-tile.
// A[4 nodes][16 k] chunk held in registers (global float4, nodes thread-exclusive).
// B staged in LDS, read as broadcast b128 (2 per k, amortized over 4 nodes).
// PREMAP: logical W[k][jh*64+jj] = ep1W[jh*64+k][jj] (cat-split of ep1 weights).
// OS: output row stride (and fold stride). Epilogue: fold/relu/scale/fp16 as flagged.
template<int K, bool PREMAP, bool FOLD, bool RELU, bool OH, bool SCALE, int OS>
__global__ void __launch_bounds__(256) k_mm(const float* __restrict__ A,
                                            const float* __restrict__ W,
                                            const float* __restrict__ fold,
                                            const float* __restrict__ rowscale,
                                            void* __restrict__ outv){
    __shared__ float Bs[K*64];
    int t = threadIdx.x;
    int jh = blockIdx.y;                   // 0 except pre-stage (0/1)
    for(int idx = t; idx < K*64; idx += 256){
        int k = idx >> 6, jj = idx & 63;
        Bs[idx] = PREMAP ? W[(jh*64 + k)*64 + jj] : W[idx];
    }
    __syncthreads();
    int nq = t & 31, jg = t >> 5;          // 32 node-quads, 8 j-groups of 8
    int n0 = blockIdx.x*128 + nq*4;
    int j0 = jg*8;
    float acc[4][8];
    #pragma unroll
    for(int a = 0; a < 4; a++)
        #pragma unroll
        for(int b = 0; b < 8; b++) acc[a][b] = 0.f;

    const float4* A4 = (const float4*)A;
    for(int kc = 0; kc < K/16; kc++){
        float4 ar[4][4];
        #pragma unroll
        for(int ni = 0; ni < 4; ni++){
            int n = n0 + ni; if(n >= NN) n = NN-1;
            const float4* ap = A4 + (size_t)n*(K/4) + kc*4;
            ar[ni][0] = ap[0]; ar[ni][1] = ap[1]; ar[ni][2] = ap[2]; ar[ni][3] = ap[3];
        }
        #pragma unroll
        for(int kk = 0; kk < 16; kk++){
            const float4* brow = (const float4*)&Bs[(kc*16+kk)*64 + j0];
            float4 b0 = brow[0], b1 = brow[1];
            #pragma unroll
            for(int ni = 0; ni < 4; ni++){
                float av = ((const float*)&ar[ni][kk>>2])[kk&3];
                acc[ni][0] = fmaf(av, b0.x, acc[ni][0]);
                acc[ni][1] = fmaf(av, b0.y, acc[ni][1]);
                acc[ni][2] = fmaf(av, b0.z, acc[ni][2]);
                acc[ni][3] = fmaf(av, b0.w, acc[ni][3]);
                acc[ni][4] = fmaf(av, b1.x, acc[ni][4]);
                acc[ni][5] = fmaf(av, b1.y, acc[ni][5]);
                acc[ni][6] = fmaf(av, b1.z, acc[ni][6]);
                acc[ni][7] = fmaf(av, b1.w, acc[ni][7]);
            }
        }
    }

    int jbase = jh*64 + j0;                // output/fold column base
    #pragma unroll
    for(int ni = 0; ni < 4; ni++){
        int n = n0 + ni;
        if(n >= NN) continue;
        float rs = SCALE ? rowscale[n] : 1.f;
        float vv[8];
        #pragma unroll
        for(int jj = 0; jj < 8; jj++){
            float v = acc[ni][jj];
            if(FOLD) v = v*fold[jbase+jj] + fold[OS + jbase + jj];
            if(RELU) v = fmaxf(v, 0.f);
            if(SCALE) v *= rs;
            vv[jj] = v;
        }
        if(OH){
            unsigned short* op = (unsigned short*)outv + (size_t)n*OS + jbase;
            ushort4 u0, u1;
            u0.x = __half_as_ushort(__float2half_rn(vv[0]));
            u0.y = __half_as_ushort(__float2half_rn(vv[1]));
            u0.z = __half_as_ushort(__float2half_rn(vv[2]));
            u0.w = __half_as_ushort(__float2half_rn(vv[3]));
            u1.x = __half_as_ushort(__float2half_rn(vv[4]));
            u1.y = __half_as_ushort(__float2half_rn(vv[5]));
            u1.z = __half_as_ushort(__float2half_rn(vv[6]));
            u1.w = __half_as_ushort(__float2half_rn(vv[7]));
            ((ushort4*)op)[0] = u0;
            ((ushort4*)op)[1] = u1;
        } else {
            float* op = (float*)outv + (size_t)n*OS + jbase;
            ((float4*)op)[0] = make_float4(vv[0], vv[1], vv[2], vv[3]);
            ((float4*)op)[1] = make_float4(vv[4], vv[5], vv[6], vv[7]);
        }
    }
}

// ---------------- GCN aggregation (pre-scaled fp16 hw'): relu(dn*(sum + self) + b) ----------------
__global__ void __launch_bounds__(256) k_agg2(const __half* __restrict__ hws,
                                              const int* __restrict__ starts,
                                              const int* __restrict__ deg,
                                              const int* __restrict__ csr,
                                              const float* __restrict__ dinv,
                                              const float* __restrict__ bias,
                                              float* __restrict__ out){
    int t = threadIdx.x, w = t>>6, f = t&63;
    int n = blockIdx.x*4 + w;
    int s = __builtin_amdgcn_readfirstlane(starts[n]);
    int d = __builtin_amdgcn_readfirstlane(deg[n]);
    float acc = 0.f;
    int i = 0;
    for(; i+7 < d; i += 8){                 // 8-way unroll for outstanding gathers
        int r0 = csr[s+i],   r1 = csr[s+i+1];
        int r2 = csr[s+i+2], r3 = csr[s+i+3];
        int r4 = csr[s+i+4], r5 = csr[s+i+5];
        int r6 = csr[s+i+6], r7 = csr[s+i+7];
        float v0 = __half2float(hws[(size_t)r0*64 + f]);
        float v1 = __half2float(hws[(size_t)r1*64 + f]);
        float v2 = __half2float(hws[(size_t)r2*64 + f]);
        float v3 = __half2float(hws[(size_t)r3*64 + f]);
        float v4 = __half2float(hws[(size_t)r4*64 + f]);
        float v5 = __half2float(hws[(size_t)r5*64 + f]);
        float v6 = __half2float(hws[(size_t)r6*64 + f]);
        float v7 = __half2float(hws[(size_t)r7*64 + f]);
        acc += v0 + v1 + v2 + v3 + v4 + v5 + v6 + v7;
    }
    for(; i < d; i++){
        int r0 = csr[s+i];
        acc += __half2float(hws[(size_t)r0*64 + f]);
    }
    float dn = dinv[n];
    float self = __half2float(hws[(size_t)n*64 + f]);
    float v = (acc + self)*dn + bias[f];
    out[(size_t)n*64 + f] = fmaxf(v, 0.f);
}

// ---------------- edge predictor: octet-cooperative ----------------
__global__ void __launch_bounds__(256) k_edge4(const __half* __restrict__ pre,
                                               const int* __restrict__ row,
                                               const int* __restrict__ col,
                                               const float* __restrict__ w2,
                                               const float* __restrict__ b2,
                                               float* __restrict__ out){
    int t = threadIdx.x, w = t>>6, j = t&63;
    int wave = blockIdx.x*4 + w;
    const int NW = EBLOCKS*4;
    const int C = (NE + NW - 1)/NW;       // contiguous chunk per wave
    int e0 = wave*C, e1 = min(e0+C, NE);
    int p = j & 7;                        // part within octet
    int oc = j >> 3;                      // octet id 0..7
    float4 w2lo = *(const float4*)(w2 + 8*p);
    float4 w2hi = *(const float4*)(w2 + 8*p + 4);
    float b2v = b2[0];
    const unsigned short* ps = (const unsigned short*)pre;

    auto edot = [&](int r, int c)->float{
        uint4 ua = *(const uint4*)(ps + (size_t)r*128 + 8*p);        // A-half dwordx4 p
        uint4 ub = *(const uint4*)(ps + (size_t)c*128 + 64 + 8*p);   // B-half dwordx4 p
        const __half2* ah = (const __half2*)&ua;
        const __half2* bh = (const __half2*)&ub;
        float2 a0 = __half22float2(ah[0]), b0 = __half22float2(bh[0]);
        float2 a1 = __half22float2(ah[1]), b1 = __half22float2(bh[1]);
        float2 a2 = __half22float2(ah[2]), b2f = __half22float2(bh[2]);
        float2 a3 = __half22float2(ah[3]), b3 = __half22float2(bh[3]);
        float z;
        z  = fmaxf(a0.x+b0.x, 0.f)*w2lo.x + fmaxf(a0.y+b0.y, 0.f)*w2lo.y;
        z  = fmaf(fmaxf(a1.x+b1.x, 0.f), w2lo.z, z);
        z  = fmaf(fmaxf(a1.y+b1.y, 0.f), w2lo.w, z);
        z  = fmaf(fmaxf(a2.x+b2f.x,0.f), w2hi.x, z);
        z  = fmaf(fmaxf(a2.y+b2f.y,0.f), w2hi.y, z);
        z  = fmaf(fmaxf(a3.x+b3.x, 0.f), w2hi.z, z);
        z  = fmaf(fmaxf(a3.y+b3.y, 0.f), w2hi.w, z);
        return z;
    };

    int e = e0;
    for(; e + 16 <= e1; e += 16){         // 2 edges in flight per thread
        int ei = e + oc, ej = e + 8 + oc;
        int r0 = row[ei], c0 = col[ei];
        int r1 = row[ej], c1 = col[ej];
        float z0 = edot(r0, c0);
        float z1 = edot(r1, c1);
        z0 += __shfl_xor(z0, 1, 64); z1 += __shfl_xor(z1, 1, 64);
        z0 += __shfl_xor(z0, 2, 64); z1 += __shfl_xor(z1, 2, 64);
        z0 += __shfl_xor(z0, 4, 64); z1 += __shfl_xor(z1, 4, 64);
        if(p == 0){
            out[ei] = 1.f/(1.f+__expf(-(z0+b2v)));
            out[ej] = 1.f/(1.f+__expf(-(z1+b2v)));
        }
    }
    for(; e < e1; e += 8){                // predicated tail
        int ei = e + oc;
        bool valid = ei < e1;
        int eic = valid ? ei : (e1-1);
        int r0 = row[eic], c0 = col[eic];
        float z0 = edot(r0, c0);
        z0 += __shfl_xor(z0, 1, 64);
        z0 += __shfl_xor(z0, 2, 64);
        z0 += __shfl_xor(z0, 4, 64);
        if(p == 0 && valid) out[ei] = 1.f/(1.f+__expf(-(z0+b2v)));
    }
}

// ---------------- launch ----------------

extern "C" void kernel_launch(void* const* d_in, const int* in_sizes, int n_in,
                              void* d_out, int out_size, void* d_ws, size_t ws_size,
                              hipStream_t stream){
    const float* x   = (const float*)d_in[0];
    const int* ei    = (const int*)d_in[1];
    const int* row   = ei;
    const int* col   = ei + NE;
    const float* encW = (const float*)d_in[2],  *encB = (const float*)d_in[3];
    const float* encG = (const float*)d_in[4],  *encBe= (const float*)d_in[5];
    const float* encM = (const float*)d_in[6],  *encV = (const float*)d_in[7];
    const float* c1W  = (const float*)d_in[8],  *c1b  = (const float*)d_in[9];
    const float* c2W  = (const float*)d_in[10], *c2b  = (const float*)d_in[11];
    const float* ep1W = (const float*)d_in[12], *ep1b = (const float*)d_in[13];
    const float* epG  = (const float*)d_in[14], *epBe = (const float*)d_in[15];
    const float* epM  = (const float*)d_in[16], *epV  = (const float*)d_in[17];
    const float* ep2W = (const float*)d_in[18], *ep2b = (const float*)d_in[19];

    char* wsc = (char*)d_ws;
    size_t o = 0;
    auto alloc = [&](size_t bytes)->void*{
        void* p = wsc + o; o += (bytes + 255) & ~(size_t)255; return p;
    };
    int*    deg     = (int*)   alloc((size_t)NN*4);
    int*    starts  = (int*)   alloc((size_t)NN*4);
    int*    bsum    = (int*)   alloc(1024*4);
    int*    bcnt    = (int*)   alloc((size_t)NBUCK*4);
    int*    csr     = (int*)   alloc((size_t)NE*4);
    uint32* staged  = (uint32*)alloc((size_t)NBUCK*BCAP*4);   // 8.0 MB
    float*  dinv    = (float*) alloc((size_t)NN*4);
    float*  foldEnc = (float*) alloc(128*4);
    float*  foldPre = (float*) alloc(256*4);
    float*  bufA    = (float*) alloc((size_t)NN*64*4);        // fp32 h buffer (25.6 MB)
    __half* bufB    = (__half*)alloc((size_t)NN*64*2);        // fp16 hw' buffer (12.8 MB)
    // pre[N,128] fp16 (25.6 MB) aliases bufA (dead after conv2 gemm)
    __half* preh    = (__half*)bufA;
    // total ~54 MB of d_ws

    float* outp = (float*)d_out;               // [NN*64] node emb | [NE] edge preds
    float* node_out = outp;
    float* edge_out = outp + (size_t)NN*64;

    hipMemsetAsync(bcnt, 0, (size_t)NBUCK*4, stream);
    k_part <<<NCHUNK,  256, 0, stream>>>(row, col, bcnt, staged);
    k_hist <<<NBUCK,   256, 0, stream>>>(bcnt, staged, deg);
    k_bsum <<<NB_SCAN, 256, 0, stream>>>(deg, bsum);
    k_top  <<<1,       512, 0, stream>>>(bsum);
    k_scan <<<NB_SCAN, 256, 0, stream>>>(deg, bsum, starts, dinv);
    k_fill2<<<NBUCK,   256, 0, stream>>>(bcnt, staged, starts, csr);
    k_const<<<1, 64, 0, stream>>>(encB, encG, encBe, encM, encV,
                                  ep1b, epG, epBe, epM, epV, foldEnc, foldPre);

    // encoder: relu(bn(x @ encW + b)) -> fp32 bufA
    k_mm<128,false,true,true,false,false,64><<<dim3(NB_MM,1), 256, 0, stream>>>
        (x, encW, foldEnc, nullptr, bufA);

    // conv1: hw' = (h @ W) * dinv -> fp16, then aggregate -> fp32
    k_mm<64,false,false,false,true,true,64><<<dim3(NB_MM,1), 256, 0, stream>>>
        (bufA, c1W, nullptr, dinv, bufB);
    k_agg2 <<<NN/4, 256, 0, stream>>>(bufB, starts, deg, csr, dinv, c1b, bufA);

    // conv2
    k_mm<64,false,false,false,true,true,64><<<dim3(NB_MM,1), 256, 0, stream>>>
        (bufA, c2W, nullptr, dinv, bufB);
    k_agg2 <<<NN/4, 256, 0, stream>>>(bufB, starts, deg, csr, dinv, c2b, node_out);

    // edge predictor precompute -> fp16 pre [A|B] interleaved (jh = blockIdx.y)
    k_mm<64,true,true,false,true,false,128><<<dim3(NB_MM,2), 256, 0, stream>>>
        (node_out, ep1W, foldPre, nullptr, preh);

    // per-edge: sigmoid(sum relu(preA[r]+preB[c])*w2 + b2), octet-cooperative
    k_edge4<<<EBLOCKS, 256, 0, stream>>>(preh, row, col, ep2W, ep2b, edge_out);
}

// Round 11
// 394.667 us; speedup vs baseline: 1.3703x; 1.3703x over previous
//
#include <hip/hip_runtime.h>
#include <hip/hip_bf16.h>
#include <hip/hip_fp16.h>

#define NN 100000
#define NE 1600000
#define FIN 128
#define HD 64
#define NB_SCAN 391    // ceil(NN/256)
#define NB_MF 1563     // ceil(NN/64): 64-row tiles
#define BSH 9          // bucket covers 512 dest nodes
#define NBUCK 196      // ceil(NN/512)
#define BCAP 10240     // per-bucket staging cap (mean 8163, sigma 128 -> +16 sigma)
#define CHUNK 4096     // edges per stage-1 block
#define NCHUNK 391     // ceil(NE/CHUNK)
#define EBLOCKS 2048   // edge-kernel blocks (8192 waves)

typedef unsigned int uint32;
typedef _Float16 half8 __attribute__((ext_vector_type(8)));
typedef float f32x4 __attribute__((ext_vector_type(4)));

// ---------------- stage 1: block-level counting sort into 196 buckets ----------------
__global__ void __launch_bounds__(256) k_part(const int* __restrict__ row,
                                              const int* __restrict__ col,
                                              int* __restrict__ bcnt,
                                              uint32* __restrict__ staged){
    __shared__ int hist[NBUCK];
    __shared__ int base[NBUCK];
    int t = threadIdx.x;
    int e0 = blockIdx.x * CHUNK;
    int e1 = min(e0 + CHUNK, NE);
    for(int i = t; i < NBUCK; i += 256) hist[i] = 0;
    __syncthreads();
    for(int e = e0 + t; e < e1; e += 256)
        atomicAdd(&hist[col[e] >> BSH], 1);
    __syncthreads();
    for(int i = t; i < NBUCK; i += 256){
        int c = hist[i];
        base[i] = (c > 0) ? atomicAdd(&bcnt[i], c) : 0;   // one global atomic per (block,bucket)
        hist[i] = 0;                                       // reuse as cursor
    }
    __syncthreads();
    for(int e = e0 + t; e < e1; e += 256){
        int c = col[e], r = row[e];
        int b = c >> BSH;
        int pos = base[b] + atomicAdd(&hist[b], 1);
        if(pos < BCAP)
            staged[(size_t)b*BCAP + pos] = ((uint32)r << BSH) | (uint32)(c & 511);
    }
}

// ---------------- stage 2a: per-bucket LDS histogram -> deg ----------------
__global__ void __launch_bounds__(256) k_hist(const int* __restrict__ bcnt,
                                              const uint32* __restrict__ staged,
                                              int* __restrict__ deg){
    __shared__ int h[512];
    int b = blockIdx.x, t = threadIdx.x;
    for(int i = t; i < 512; i += 256) h[i] = 0;
    __syncthreads();
    int cnt = min(bcnt[b], BCAP);
    const uint32* st = staged + (size_t)b*BCAP;
    for(int i = t; i < cnt; i += 256) atomicAdd(&h[st[i] & 511u], 1);
    __syncthreads();
    for(int i = t; i < 512; i += 256){
        int n = b*512 + i;
        if(n < NN) deg[n] = h[i];
    }
}

// ---------------- scan chain (deg -> starts, dinv) ----------------
__global__ void k_bsum(const int* __restrict__ deg, int* __restrict__ bsum){
    __shared__ int r[256];
    int t = threadIdx.x; int i = blockIdx.x*256 + t;
    r[t] = (i < NN) ? deg[i] : 0;
    __syncthreads();
    for(int off=128; off>0; off>>=1){ if(t<off) r[t]+=r[t+off]; __syncthreads(); }
    if(t==0) bsum[blockIdx.x] = r[0];
}

__global__ void k_top(int* __restrict__ bsum){
    __shared__ int s[512];
    int t = threadIdx.x;
    int v = (t < NB_SCAN) ? bsum[t] : 0;
    s[t] = v; __syncthreads();
    for(int off=1; off<512; off<<=1){
        int a = (t>=off)? s[t-off] : 0;
        __syncthreads();
        s[t] += a;
        __syncthreads();
    }
    if(t < NB_SCAN) bsum[t] = s[t] - v;   // exclusive scan of block sums
}

__global__ void k_scan(const int* __restrict__ deg, const int* __restrict__ bsum,
                       int* __restrict__ starts, float* __restrict__ dinv){
    __shared__ int s[256];
    int t = threadIdx.x; int i = blockIdx.x*256 + t;
    int d = (i<NN)? deg[i] : 0;
    s[t] = d; __syncthreads();
    for(int off=1; off<256; off<<=1){
        int a = (t>=off)? s[t-off] : 0;
        __syncthreads();
        s[t] += a;
        __syncthreads();
    }
    if(i < NN){
        starts[i] = bsum[blockIdx.x] + s[t] - d;   // exclusive
        dinv[i] = rsqrtf((float)(d + 1));          // +1 self-loop
    }
}

// ---------------- stage 2b: per-bucket LDS scatter, coalesced csr write ----------------
__global__ void __launch_bounds__(256) k_fill2(const int* __restrict__ bcnt,
                                               const uint32* __restrict__ staged,
                                               const int* __restrict__ starts,
                                               int* __restrict__ csr){
    __shared__ int cur[512];
    __shared__ int lcsr[BCAP];
    int b = blockIdx.x, t = threadIdx.x;
    int n0 = b*512;
    int base = starts[n0];
    for(int i = t; i < 512; i += 256){
        int n = n0 + i;
        cur[i] = (n < NN) ? starts[n] - base : 0;
    }
    __syncthreads();
    int cnt = min(bcnt[b], BCAP);
    const uint32* st = staged + (size_t)b*BCAP;
    for(int i = t; i < cnt; i += 256){
        uint32 u = st[i];
        int p = atomicAdd(&cur[u & 511u], 1);
        lcsr[p] = (int)(u >> BSH);
    }
    __syncthreads();
    for(int i = t; i < cnt; i += 256) csr[base + i] = lcsr[i];
}

// ---------------- BN constant folding ----------------
__global__ void k_const(const float* __restrict__ encB, const float* __restrict__ encG,
                        const float* __restrict__ encBe, const float* __restrict__ encM,
                        const float* __restrict__ encV,
                        const float* __restrict__ ep1b, const float* __restrict__ epG,
                        const float* __restrict__ epBe, const float* __restrict__ epM,
                        const float* __restrict__ epV,
                        float* __restrict__ foldEnc, float* __restrict__ foldPre){
    int j = threadIdx.x;
    if(j < 64){
        float s = encG[j]*rsqrtf(encV[j]+1e-5f);
        foldEnc[j]      = s;
        foldEnc[64+j]   = (encB[j]-encM[j])*s + encBe[j];
        float sp = epG[j]*rsqrtf(epV[j]+1e-5f);
        foldPre[j]      = sp;
        foldPre[64+j]   = sp;
        foldPre[128+j]  = sp*(ep1b[j]-epM[j]) + epBe[j];
        foldPre[192+j]  = 0.f;
    }
}

// ---------------- weight prep: fp16, transposed [n][K] for MFMA B-frags ----------------
// wt layout (halves): encT[64][128] @0 | c1T[64][64] @8192 | c2T[64][64] @12288 |
//                     ep1T half0 [64][64] @16384 | ep1T half1 @20480
__global__ void k_wprep(const float* __restrict__ encW, const float* __restrict__ c1W,
                        const float* __restrict__ c2W, const float* __restrict__ ep1W,
                        _Float16* __restrict__ wt){
    int i = blockIdx.x*256 + threadIdx.x;   // 96*256 = 24576
    if(i < 8192){
        int n = i >> 7, k = i & 127;
        wt[i] = (_Float16)encW[k*64 + n];
    } else if(i < 12288){
        int j = i - 8192; int n = j >> 6, k = j & 63;
        wt[i] = (_Float16)c1W[k*64 + n];
    } else if(i < 16384){
        int j = i - 12288; int n = j >> 6, k = j & 63;
        wt[i] = (_Float16)c2W[k*64 + n];
    } else if(i < 24576){
        int j = i - 16384; int h = j >> 12; int jj = j & 4095;
        int n = jj >> 6, k = jj & 63;
        wt[i] = (_Float16)ep1W[(h*64 + k)*64 + n];   // logical W[k][h*64+n] = ep1W[h*64+k][n]
    }
}

// ---------------- MFMA GEMM: 64 rows x 64 cols per block, K fully in LDS ----------------
// 4 waves; wave w computes rows w*16..+16 x all 64 cols via 4 16x16 tiles.
// A: m=lane&15, k=quad*8+j (quad=lane>>4); B dual (n=lane&15); C/D: col=lane&15, row=quad*4+reg.
// AF32: A source is fp32 (cvt during LDS stage). fold: [scale(OS)|shift(OS)].
template<int K, bool AF32, bool FOLD, bool RELU, bool SCALE, int OS>
__global__ void __launch_bounds__(256) k_mfma(const void* __restrict__ Ain,
                                              const _Float16* __restrict__ Bt,
                                              const float* __restrict__ fold,
                                              const float* __restrict__ rowscale,
                                              _Float16* __restrict__ outh){
    constexpr int PS = K + 8;              // padded row stride (halves); row bytes %16==0
    __shared__ _Float16 As[64*PS];
    __shared__ _Float16 Bs[64*PS];
    int t = threadIdx.x;
    int m0 = blockIdx.x*64;
    int jh = blockIdx.y;
    // stage B (transposed fp16 [64][K], contiguous in global)
    {
        const _Float16* src = Bt + (size_t)jh*64*K;
        for(int idx = t; idx < 64*(K/8); idx += 256){
            int n = idx/(K/8), c = idx%(K/8);
            *(half8*)&Bs[n*PS + c*8] = *(const half8*)&src[n*K + c*8];
        }
    }
    // stage A
    if(AF32){
        const float* A = (const float*)Ain;
        for(int idx = t; idx < 64*(K/4); idx += 256){
            int r = idx/(K/4), c = idx%(K/4);
            int rowi = m0 + r; if(rowi >= NN) rowi = NN-1;
            float4 v = *(const float4*)&A[(size_t)rowi*K + c*4];
            _Float16* d = &As[r*PS + c*4];
            d[0]=(_Float16)v.x; d[1]=(_Float16)v.y; d[2]=(_Float16)v.z; d[3]=(_Float16)v.w;
        }
    } else {
        const _Float16* A = (const _Float16*)Ain;
        for(int idx = t; idx < 64*(K/8); idx += 256){
            int r = idx/(K/8), c = idx%(K/8);
            int rowi = m0 + r; if(rowi >= NN) rowi = NN-1;
            *(half8*)&As[r*PS + c*8] = *(const half8*)&A[(size_t)rowi*K + c*8];
        }
    }
    __syncthreads();
    int w = t>>6, l = t&63;
    int lm = l&15, q = l>>4;
    f32x4 acc0 = {0.f,0.f,0.f,0.f}, acc1 = {0.f,0.f,0.f,0.f};
    f32x4 acc2 = {0.f,0.f,0.f,0.f}, acc3 = {0.f,0.f,0.f,0.f};
    const _Float16* arow = &As[(w*16+lm)*PS + q*8];
    const _Float16* brow = &Bs[lm*PS + q*8];
    #pragma unroll
    for(int ks = 0; ks < K/32; ks++){
        half8 a  = *(const half8*)(arow + ks*32);
        half8 b0 = *(const half8*)(brow + ks*32);
        half8 b1 = *(const half8*)(brow + 16*PS + ks*32);
        half8 b2 = *(const half8*)(brow + 32*PS + ks*32);
        half8 b3 = *(const half8*)(brow + 48*PS + ks*32);
        acc0 = __builtin_amdgcn_mfma_f32_16x16x32_f16(a, b0, acc0, 0,0,0);
        acc1 = __builtin_amdgcn_mfma_f32_16x16x32_f16(a, b1, acc1, 0,0,0);
        acc2 = __builtin_amdgcn_mfma_f32_16x16x32_f16(a, b2, acc2, 0,0,0);
        acc3 = __builtin_amdgcn_mfma_f32_16x16x32_f16(a, b3, acc3, 0,0,0);
    }
    f32x4 accs[4] = {acc0, acc1, acc2, acc3};
    #pragma unroll
    for(int nt = 0; nt < 4; nt++){
        int col = nt*16 + lm;
        int jcol = jh*64 + col;
        float fs = FOLD ? fold[jcol] : 0.f;
        float fb = FOLD ? fold[OS + jcol] : 0.f;
        #pragma unroll
        for(int r = 0; r < 4; r++){
            int rowi = m0 + w*16 + q*4 + r;
            if(rowi >= NN) continue;
            float v = accs[nt][r];
            if(FOLD) v = v*fs + fb;
            if(RELU) v = fmaxf(v, 0.f);
            if(SCALE) v *= rowscale[rowi];
            outh[(size_t)rowi*OS + jcol] = (_Float16)v;
        }
    }
}

// ---------------- GCN aggregation (pre-scaled fp16 hw'): relu(dn*(sum+self)+b) ----------------
// writes fp16 (next dense stage's A) and optionally fp32 (node_embeddings output)
__global__ void __launch_bounds__(256) k_agg3(const __half* __restrict__ hws,
                                              const int* __restrict__ starts,
                                              const int* __restrict__ deg,
                                              const int* __restrict__ csr,
                                              const float* __restrict__ dinv,
                                              const float* __restrict__ bias,
                                              _Float16* __restrict__ outh,
                                              float* __restrict__ outf){
    int t = threadIdx.x, w = t>>6, f = t&63;
    int n = blockIdx.x*4 + w;
    int s = __builtin_amdgcn_readfirstlane(starts[n]);
    int d = __builtin_amdgcn_readfirstlane(deg[n]);
    float acc = 0.f;
    int i = 0;
    for(; i+7 < d; i += 8){                 // 8-way unroll for outstanding gathers
        int r0 = csr[s+i],   r1 = csr[s+i+1];
        int r2 = csr[s+i+2], r3 = csr[s+i+3];
        int r4 = csr[s+i+4], r5 = csr[s+i+5];
        int r6 = csr[s+i+6], r7 = csr[s+i+7];
        float v0 = __half2float(hws[(size_t)r0*64 + f]);
        float v1 = __half2float(hws[(size_t)r1*64 + f]);
        float v2 = __half2float(hws[(size_t)r2*64 + f]);
        float v3 = __half2float(hws[(size_t)r3*64 + f]);
        float v4 = __half2float(hws[(size_t)r4*64 + f]);
        float v5 = __half2float(hws[(size_t)r5*64 + f]);
        float v6 = __half2float(hws[(size_t)r6*64 + f]);
        float v7 = __half2float(hws[(size_t)r7*64 + f]);
        acc += v0 + v1 + v2 + v3 + v4 + v5 + v6 + v7;
    }
    for(; i < d; i++){
        int r0 = csr[s+i];
        acc += __half2float(hws[(size_t)r0*64 + f]);
    }
    float dn = dinv[n];
    float self = __half2float(hws[(size_t)n*64 + f]);
    float v = (acc + self)*dn + bias[f];
    v = fmaxf(v, 0.f);
    outh[(size_t)n*64 + f] = (_Float16)v;
    if(outf) outf[(size_t)n*64 + f] = v;
}

// ---------------- edge predictor: octet-cooperative ----------------
__global__ void __launch_bounds__(256) k_edge4(const __half* __restrict__ pre,
                                               const int* __restrict__ row,
                                               const int* __restrict__ col,
                                               const float* __restrict__ w2,
                                               const float* __restrict__ b2,
                                               float* __restrict__ out){
    int t = threadIdx.x, w = t>>6, j = t&63;
    int wave = blockIdx.x*4 + w;
    const int NW = EBLOCKS*4;
    const int C = (NE + NW - 1)/NW;       // contiguous chunk per wave
    int e0 = wave*C, e1 = min(e0+C, NE);
    int p = j & 7;                        // part within octet
    int oc = j >> 3;                      // octet id 0..7
    float4 w2lo = *(const float4*)(w2 + 8*p);
    float4 w2hi = *(const float4*)(w2 + 8*p + 4);
    float b2v = b2[0];
    const unsigned short* ps = (const unsigned short*)pre;

    auto edot = [&](int r, int c)->float{
        uint4 ua = *(const uint4*)(ps + (size_t)r*128 + 8*p);        // A-half dwordx4 p
        uint4 ub = *(const uint4*)(ps + (size_t)c*128 + 64 + 8*p);   // B-half dwordx4 p
        const __half2* ah = (const __half2*)&ua;
        const __half2* bh = (const __half2*)&ub;
        float2 a0 = __half22float2(ah[0]), b0 = __half22float2(bh[0]);
        float2 a1 = __half22float2(ah[1]), b1 = __half22float2(bh[1]);
        float2 a2 = __half22float2(ah[2]), b2f = __half22float2(bh[2]);
        float2 a3 = __half22float2(ah[3]), b3 = __half22float2(bh[3]);
        float z;
        z  = fmaxf(a0.x+b0.x, 0.f)*w2lo.x + fmaxf(a0.y+b0.y, 0.f)*w2lo.y;
        z  = fmaf(fmaxf(a1.x+b1.x, 0.f), w2lo.z, z);
        z  = fmaf(fmaxf(a1.y+b1.y, 0.f), w2lo.w, z);
        z  = fmaf(fmaxf(a2.x+b2f.x,0.f), w2hi.x, z);
        z  = fmaf(fmaxf(a2.y+b2f.y,0.f), w2hi.y, z);
        z  = fmaf(fmaxf(a3.x+b3.x, 0.f), w2hi.z, z);
        z  = fmaf(fmaxf(a3.y+b3.y, 0.f), w2hi.w, z);
        return z;
    };

    int e = e0;
    for(; e + 16 <= e1; e += 16){         // 2 edges in flight per thread
        int ei = e + oc, ej = e + 8 + oc;
        int r0 = row[ei], c0 = col[ei];
        int r1 = row[ej], c1 = col[ej];
        float z0 = edot(r0, c0);
        float z1 = edot(r1, c1);
        z0 += __shfl_xor(z0, 1, 64); z1 += __shfl_xor(z1, 1, 64);
        z0 += __shfl_xor(z0, 2, 64); z1 += __shfl_xor(z1, 2, 64);
        z0 += __shfl_xor(z0, 4, 64); z1 += __shfl_xor(z1, 4, 64);
        if(p == 0){
            out[ei] = 1.f/(1.f+__expf(-(z0+b2v)));
            out[ej] = 1.f/(1.f+__expf(-(z1+b2v)));
        }
    }
    for(; e < e1; e += 8){                // predicated tail
        int ei = e + oc;
        bool valid = ei < e1;
        int eic = valid ? ei : (e1-1);
        int r0 = row[eic], c0 = col[eic];
        float z0 = edot(r0, c0);
        z0 += __shfl_xor(z0, 1, 64);
        z0 += __shfl_xor(z0, 2, 64);
        z0 += __shfl_xor(z0, 4, 64);
        if(p == 0 && valid) out[ei] = 1.f/(1.f+__expf(-(z0+b2v)));
    }
}

// ---------------- launch ----------------

extern "C" void kernel_launch(void* const* d_in, const int* in_sizes, int n_in,
                              void* d_out, int out_size, void* d_ws, size_t ws_size,
                              hipStream_t stream){
    const float* x   = (const float*)d_in[0];
    const int* ei    = (const int*)d_in[1];
    const int* row   = ei;
    const int* col   = ei + NE;
    const float* encW = (const float*)d_in[2],  *encB = (const float*)d_in[3];
    const float* encG = (const float*)d_in[4],  *encBe= (const float*)d_in[5];
    const float* encM = (const float*)d_in[6],  *encV = (const float*)d_in[7];
    const float* c1W  = (const float*)d_in[8],  *c1b  = (const float*)d_in[9];
    const float* c2W  = (const float*)d_in[10], *c2b  = (const float*)d_in[11];
    const float* ep1W = (const float*)d_in[12], *ep1b = (const float*)d_in[13];
    const float* epG  = (const float*)d_in[14], *epBe = (const float*)d_in[15];
    const float* epM  = (const float*)d_in[16], *epV  = (const float*)d_in[17];
    const float* ep2W = (const float*)d_in[18], *ep2b = (const float*)d_in[19];

    char* wsc = (char*)d_ws;
    size_t o = 0;
    auto alloc = [&](size_t bytes)->void*{
        void* p = wsc + o; o += (bytes + 255) & ~(size_t)255; return p;
    };
    int*      deg     = (int*)     alloc((size_t)NN*4);
    int*      starts  = (int*)     alloc((size_t)NN*4);
    int*      bsum    = (int*)     alloc(1024*4);
    int*      bcnt    = (int*)     alloc((size_t)NBUCK*4);
    int*      csr     = (int*)     alloc((size_t)NE*4);
    uint32*   staged  = (uint32*)  alloc((size_t)NBUCK*BCAP*4);   // 8.0 MB
    float*    dinv    = (float*)   alloc((size_t)NN*4);
    float*    foldEnc = (float*)   alloc(128*4);
    float*    foldPre = (float*)   alloc(256*4);
    _Float16* wt      = (_Float16*)alloc(24576*2);                // fp16 transposed weights
    _Float16* bufA    = (_Float16*)alloc((size_t)NN*64*2);        // fp16 h buffer (12.8 MB)
    _Float16* bufB    = (_Float16*)alloc((size_t)NN*64*2);        // fp16 hw' buffer (12.8 MB)
    _Float16* preh    = (_Float16*)alloc((size_t)NN*128*2);       // fp16 pre [A|B] (25.6 MB)
    // total ~67 MB of d_ws

    float* outp = (float*)d_out;               // [NN*64] node emb | [NE] edge preds
    float* node_out = outp;
    float* edge_out = outp + (size_t)NN*64;

    hipMemsetAsync(bcnt, 0, (size_t)NBUCK*4, stream);
    k_part <<<NCHUNK,  256, 0, stream>>>(row, col, bcnt, staged);
    k_hist <<<NBUCK,   256, 0, stream>>>(bcnt, staged, deg);
    k_bsum <<<NB_SCAN, 256, 0, stream>>>(deg, bsum);
    k_top  <<<1,       512, 0, stream>>>(bsum);
    k_scan <<<NB_SCAN, 256, 0, stream>>>(deg, bsum, starts, dinv);
    k_fill2<<<NBUCK,   256, 0, stream>>>(bcnt, staged, starts, csr);
    k_const<<<1, 64, 0, stream>>>(encB, encG, encBe, encM, encV,
                                  ep1b, epG, epBe, epM, epV, foldEnc, foldPre);
    k_wprep<<<96, 256, 0, stream>>>(encW, c1W, c2W, ep1W, wt);

    // encoder: relu(bn(x @ encW + b)) -> fp16 bufA   (A fp32, cvt in stage)
    k_mfma<128,true,true,true,false,64><<<dim3(NB_MF,1), 256, 0, stream>>>
        (x, wt, foldEnc, nullptr, bufA);

    // conv1: hw' = (h0 @ c1W) * dinv -> fp16 bufB; aggregate -> h1 fp16 bufA
    k_mfma<64,false,false,false,true,64><<<dim3(NB_MF,1), 256, 0, stream>>>
        (bufA, wt + 8192, nullptr, dinv, bufB);
    k_agg3 <<<NN/4, 256, 0, stream>>>((const __half*)bufB, starts, deg, csr, dinv, c1b,
                                      bufA, nullptr);

    // conv2: -> h2 fp16 bufA + fp32 node_out (d_out)
    k_mfma<64,false,false,false,true,64><<<dim3(NB_MF,1), 256, 0, stream>>>
        (bufA, wt + 12288, nullptr, dinv, bufB);
    k_agg3 <<<NN/4, 256, 0, stream>>>((const __half*)bufB, starts, deg, csr, dinv, c2b,
                                      bufA, node_out);

    // edge predictor precompute: pre[n] = [s*(h2@W1top)+cst | s*(h2@W1bot)] fp16 (jh = blockIdx.y)
    k_mfma<64,false,true,false,false,128><<<dim3(NB_MF,2), 256, 0, stream>>>
        (bufA, wt + 16384, foldPre, nullptr, preh);

    // per-edge: sigmoid(sum relu(preA[r]+preB[c])*w2 + b2), octet-cooperative
    k_edge4<<<EBLOCKS, 256, 0, stream>>>((const __half*)preh, row, col, ep2W, ep2b, edge_out);
}